// Round 8
// baseline (317.842 us; speedup 1.0000x reference)
//
#include <hip/hip_runtime.h>
#include <hip/hip_bf16.h>

// CRF loss via associative chunked scan (MFMA layouts verified R2-R7).
// R8: back to the measured-best R3 loop shape (intrinsic MFMA, per-step
// repack via pktrunc+permlane32_swap), with the two changes that measured
// positive in isolation: launch_bounds(256,2) -> 128-reg budget so the MFMA
// web homes in arch VGPRs (R7: (256,2) raised VGPR 40->64 & VALUBusy 39->45;
// (256,4) in R4-R6 forced AGPR moves), and CHS=4 -> 16384 one-chain waves
// (2x R3's TLP, shorter chunks) for latency hiding. Gold gather hoisted.

constexpr int BN = 1024, TN = 1024, LN = 32;
constexpr float KSHIFT = 8.5f;     // per-step factors ~e^{-2}: monotone decay
constexpr float LN2F   = 0.69314718056f;

typedef __attribute__((ext_vector_type(8)))  short bf16x8;
typedef __attribute__((ext_vector_type(16))) float f32x16;
typedef __attribute__((ext_vector_type(2)))  float f32x2;

union BU { bf16x8 v; unsigned u[4]; };

// pack two f32 -> (bf16(a) | bf16(b)<<16) by truncation: one v_perm_b32
static __device__ __forceinline__ unsigned pktrunc(float a, float b) {
    return __builtin_amdgcn_perm(__float_as_uint(b), __float_as_uint(a), 0x07060302u);
}
// v_permlane32_swap_b32: a.row1 <-> b.row0 (register-only cross-half exchange)
#define PLSWAP(a, b) asm("v_permlane32_swap_b32 %0, %1" : "+v"(a), "+v"(b))

// ---------------- Phase 1: chunk transfer-matrix products ----------------
__global__ __launch_bounds__(256, 2) void crf_chunk(
    const float* __restrict__ feat,   // [B][T][L]
    const float* __restrict__ trans,  // [L][L]
    const int*   __restrict__ lab,    // [B][T]
    float* __restrict__ ws,           // [B*CH][32][32] log-space products
    float* __restrict__ out,          // [1] (gold subtracted here)
    int CHS)
{
    const int CH = 1 << CHS, LEN = TN >> CHS;
    const int l = threadIdx.x & 63, n = l & 31, h = l >> 5;
    const int gid = blockIdx.x * 4 + (threadIdx.x >> 6);   // wave id = chunk id
    const int c = gid & (CH - 1), b = gid >> CHS;

    const float* __restrict__ fb = feat + (size_t)b * TN * LN;
    const int*   __restrict__ lb = lab  + (size_t)b * TN;

    const int start = c * LEN, te = start + LEN;
    const int tm = (c == 0) ? 2 : start;   // chunk 0: t=1 folded into alpha_1

    // ---- gold path: vectorized gather, once per chunk (off the chain) ----
    {
        float gsum = 0.f;
        for (int r = 0; r < LEN; r += 64) {
            int t = start + r + l;                 // t <= te-1 by construction
            if (t >= 1) {                          // excludes only t=0 (chunk 0)
                int cur = lb[t];
                gsum += trans[cur * LN + lb[t - 1]] + fb[(size_t)t * LN + cur];
            }
        }
        #pragma unroll
        for (int s = 32; s; s >>= 1) gsum += __shfl_xor(gsum, s, 64);
        if (l == 0) atomicAdd(out, -gsum * (1.0f / (float)BN));
    }

    // A-operand constants as pairs: EA for k=8h+2r(+1), EB for k=16+8h+2r(+1)
    f32x2 EA[4], EB[4];
    #pragma unroll
    for (int r = 0; r < 4; ++r) {
        EA[r][0] = __expf(trans[n * LN + 8 * h + 2 * r]          - KSHIFT);
        EA[r][1] = __expf(trans[n * LN + 8 * h + 2 * r + 1]      - KSHIFT);
        EB[r][0] = __expf(trans[n * LN + 16 + 8 * h + 2 * r]     - KSHIFT);
        EB[r][1] = __expf(trans[n * LN + 16 + 8 * h + 2 * r + 1] - KSHIFT);
    }

    // Running product as B operand (lane -> col n, k=8h+e); init Identity.
    BU B1, B2;
    #pragma unroll
    for (int r = 0; r < 4; ++r) {
        int k0 = 8 * h + 2 * r, k1 = k0 + 1;
        B1.u[r] = (k0 == n ? 0x3F80u : 0u) | ((k1 == n ? 0x3F80u : 0u) << 16);
        B2.u[r] = (k0 + 16 == n ? 0x3F80u : 0u) | ((k1 + 16 == n ? 0x3F80u : 0u) << 16);
    }

    // ---- feature pipeline: depth 3 ----
    float fc  = fb[(size_t)tm * LN + n];
    float fn1 = fb[(size_t)(tm + 1) * LN + n];
    float fn2 = fb[(size_t)(tm + 2) * LN + n];

    // A(tm) built in prologue
    BU A1, A2, A1n, A2n;
    {
        float F = __expf(fc);
        f32x2 F2; F2[0] = F; F2[1] = F;
        #pragma unroll
        for (int r = 0; r < 4; ++r) {
            f32x2 pa = EA[r] * F2;
            f32x2 pb = EB[r] * F2;
            A1.u[r] = pktrunc(pa[0], pa[1]);
            A2.u[r] = pktrunc(pb[0], pb[1]);
        }
    }

    int sc = 0;                   // accumulated pow2 exponent (per column)
    f32x16 C;

    #pragma unroll 2
    for (int t = tm; t < te; ++t) {
        // ---- prefetch feat[t+3] (clamped; vector load, in-order vmcnt) ----
        const int tp = (t + 3 < te) ? (t + 3) : (te - 1);
        float fl = fb[(size_t)tp * LN + n];

        // ---- step t: two chained MFMAs (K=32) ----
        f32x16 Z;
        #pragma unroll
        for (int i = 0; i < 16; ++i) Z[i] = 0.f;
        C = __builtin_amdgcn_mfma_f32_32x32x16_bf16(A1.v, B1.v, Z, 0, 0, 0);
        C = __builtin_amdgcn_mfma_f32_32x32x16_bf16(A2.v, B2.v, C, 0, 0, 0);

        // ---- build A(t+1): independent of C, fills the MFMA shadow ----
        float F = __expf(fn1);
        f32x2 F2; F2[0] = F; F2[1] = F;
        #pragma unroll
        for (int r = 0; r < 4; ++r) {
            f32x2 pa = EA[r] * F2;
            f32x2 pb = EB[r] * F2;
            A1n.u[r] = pktrunc(pa[0], pa[1]);
            A2n.u[r] = pktrunc(pb[0], pb[1]);
        }

        // ---- per-column pow2 rescale every 8 steps (exact; diag commutes) ----
        if ((t & 7) == 7) {
            float cm = C[0];
            #pragma unroll
            for (int i = 1; i < 16; ++i) cm = fmaxf(cm, C[i]);
            unsigned x = __float_as_uint(cm), y = x;
            PLSWAP(x, y);                          // column consensus across halves
            cm = fmaxf(__uint_as_float(x), __uint_as_float(y));
            cm = fmaxf(cm, 1e-30f);
            int ex; frexpf(cm, &ex);
            sc += ex;
            #pragma unroll
            for (int i = 0; i < 16; ++i) C[i] = ldexpf(C[i], -ex);
        }

        // ---- C (col=l&31, row=(r&3)+8*(r>>2)+4h) -> next-step B operands ----
        unsigned PK[8];
        #pragma unroll
        for (int r = 0; r < 8; ++r) PK[r] = pktrunc(C[2 * r], C[2 * r + 1]);
        PLSWAP(PK[0], PK[2]);  PLSWAP(PK[1], PK[3]);
        PLSWAP(PK[4], PK[6]);  PLSWAP(PK[5], PK[7]);
        B1.u[0] = PK[0]; B1.u[1] = PK[1]; B1.u[2] = PK[2]; B1.u[3] = PK[3];
        B2.u[0] = PK[4]; B2.u[1] = PK[5]; B2.u[2] = PK[6]; B2.u[3] = PK[7];

        // ---- rotate pipelines (unroll 2 -> renames, not movs) ----
        A1 = A1n; A2 = A2n;
        fn1 = fn2; fn2 = fl;
    }

    // write log-space chunk matrix: log(true) = ln(C) + sc*ln2 + K*steps
    const float add = KSHIFT * (float)(te - tm) + (float)sc * LN2F;
    float* __restrict__ w = ws + ((size_t)gid << 10);
    #pragma unroll
    for (int r = 0; r < 16; ++r) {
        int row = (r & 3) + 8 * (r >> 2) + 4 * h;
        float v = C[r];
        w[row * LN + n] = (v > 0.f) ? (__logf(v) + add) : -10000.0f;
    }
}

// ---------------- Phase 2: log-space combine + final lse ----------------
__global__ __launch_bounds__(64) void crf_combine(
    const float* __restrict__ trans,
    const float* __restrict__ feat,
    const float* __restrict__ ws,
    float* __restrict__ out,
    int CHS)
{
    const int CH = 1 << CHS;
    const int l = threadIdx.x & 63, i = l & 31;
    const int seq = blockIdx.x * 2 + (l >> 5);
    const int bb = (l & 32) << 2;   // group-local bpermute base

    // alpha_1[i] = trans[i][0] + feat[1][i]  (exact)
    float alpha = trans[i * LN] + feat[(size_t)seq * TN * LN + LN + i];
    const float* __restrict__ wsb = ws + ((size_t)seq << (10 + CHS));

    for (int c = 0; c < CH; ++c) {
        const float4* Mr = (const float4*)(wsb + (c << 10) + i * LN);
        float vv[32];
        #pragma unroll
        for (int q = 0; q < 8; ++q) {
            float4 m4 = Mr[q];
            vv[4 * q + 0] = m4.x; vv[4 * q + 1] = m4.y;
            vv[4 * q + 2] = m4.z; vv[4 * q + 3] = m4.w;
        }
        float mx = -1e30f;
        #pragma unroll
        for (int j = 0; j < 32; ++j) {
            int r = __builtin_amdgcn_ds_bpermute(bb + (j << 2), __float_as_int(alpha));
            vv[j] += __int_as_float(r);
            mx = fmaxf(mx, vv[j]);
        }
        float s = 0.f;
        #pragma unroll
        for (int j = 0; j < 32; ++j) s += __expf(vv[j] - mx);
        alpha = mx + __logf(s);
    }

    // forward score = lse over 32 states
    float m = alpha;
    #pragma unroll
    for (int s = 16; s; s >>= 1) m = fmaxf(m, __shfl_xor(m, s, 32));
    float es = __expf(alpha - m);
    #pragma unroll
    for (int s = 16; s; s >>= 1) es += __shfl_xor(es, s, 32);
    float fs = m + __logf(es);

    if (i == 0) atomicAdd(out, fs * (1.0f / (float)BN));
}

extern "C" void kernel_launch(void* const* d_in, const int* in_sizes, int n_in,
                              void* d_out, int out_size, void* d_ws, size_t ws_size,
                              hipStream_t stream) {
    const float* features    = (const float*)d_in[0];
    const float* transitions = (const float*)d_in[1];
    const int*   labels      = (const int*)d_in[2];
    float* out = (float*)d_out;
    float* ws  = (float*)d_ws;

    // pick largest CH in {16,8,4,2,1} whose chunk-matrix scratch fits ws
    int CHS = 4;
    while (CHS > 0 && ws_size < (((size_t)BN << CHS) * (LN * LN * 4))) --CHS;
    const int CH = 1 << CHS;

    hipMemsetAsync(out, 0, sizeof(float), stream);
    crf_chunk<<<dim3((BN * CH) / 4), dim3(256), 0, stream>>>(
        features, transitions, labels, ws, out, CHS);
    crf_combine<<<dim3(BN / 2), dim3(64), 0, stream>>>(
        transitions, features, ws, out, CHS);
}

// Round 9
// 255.069 us; speedup vs baseline: 1.2461x; 1.2461x over previous
//
#include <hip/hip_runtime.h>
#include <hip/hip_bf16.h>

// CRF loss via associative chunked scan (MFMA layouts verified R2-R8).
// R9 = R3 (the measured-best loop: 194us chunk, VALUBusy 65%) + exactly ONE
// delta: the gold path is hoisted to a once-per-chunk vectorized gather,
// removing the per-iteration scalar-load chain (lb[t] -> trans/feat s_loads)
// whose s_waitcnt lgkmcnt(0) drain was the main issue-idle in R3's counters.
// Everything else matches R3: CHS=3, launch_bounds(256) only, in-loop
// A-build, depth-2 feature pipe, rescale every 8, hoisted ZR accumulator.

constexpr int BN = 1024, TN = 1024, LN = 32;
constexpr float KSHIFT = 8.5f;     // per-step factors ~e^{-2}: monotone decay
constexpr float LN2F   = 0.69314718056f;

typedef __attribute__((ext_vector_type(8)))  short bf16x8;
typedef __attribute__((ext_vector_type(16))) float f32x16;

// pack two f32 -> (bf16(a) | bf16(b)<<16) by truncation: one v_perm_b32
static __device__ __forceinline__ unsigned pktrunc(float a, float b) {
    return __builtin_amdgcn_perm(__float_as_uint(b), __float_as_uint(a), 0x07060302u);
}
// v_permlane32_swap_b32: a.row1 <-> b.row0 (register-only cross-half exchange)
#define PLSWAP(a, b) asm("v_permlane32_swap_b32 %0, %1" : "+v"(a), "+v"(b))

// ---------------- Phase 1: chunk transfer-matrix products ----------------
__global__ __launch_bounds__(256) void crf_chunk(
    const float* __restrict__ feat,   // [B][T][L]
    const float* __restrict__ trans,  // [L][L]
    const int*   __restrict__ lab,    // [B][T]
    float* __restrict__ ws,           // [B*CH][32][32] log-space products
    float* __restrict__ out,          // [1] (gold subtracted here)
    int CHS)
{
    const int CH = 1 << CHS, LEN = TN >> CHS;
    const int l = threadIdx.x & 63, n = l & 31, h = l >> 5;
    const int wid = __builtin_amdgcn_readfirstlane((int)(threadIdx.x >> 6));
    const int gid = blockIdx.x * 4 + wid;            // wave id = chunk id
    const int c = gid & (CH - 1), b = gid >> CHS;

    const float* __restrict__ fb = feat + (size_t)b * TN * LN;
    const int*   __restrict__ lb = lab  + (size_t)b * TN;

    const int start = c * LEN, te = start + LEN;
    const int tm = (c == 0) ? 2 : start;   // chunk 0: t=1 folded into alpha_1

    // ---- gold path: vectorized gather, once per chunk (no in-loop scalars) ----
    {
        float gsum = 0.f;
        for (int r = 0; r < LEN; r += 64) {
            int t = start + r + l;                 // t <= te-1 by construction
            if (t >= 1) {                          // excludes only t=0 (chunk 0)
                int cur = lb[t];
                gsum += trans[cur * LN + lb[t - 1]] + fb[(size_t)t * LN + cur];
            }
        }
        #pragma unroll
        for (int s = 32; s; s >>= 1) gsum += __shfl_xor(gsum, s, 64);
        if (l == 0) atomicAdd(out, -gsum * (1.0f / (float)BN));
    }

    // A-operand constants: E[e] = exp(trans[n][k(e)] - K); lane -> row m=l&31, k=8h+e.
    float E[16];
    #pragma unroll
    for (int e = 0; e < 8; ++e) E[e]     = __expf(trans[n * LN + 8 * h + e]      - KSHIFT);
    #pragma unroll
    for (int e = 0; e < 8; ++e) E[8 + e] = __expf(trans[n * LN + 16 + 8 * h + e] - KSHIFT);

    // Running product as B operand (lane -> col n, k=8h+e); init Identity.
    union BU { bf16x8 v; unsigned u[4]; } B1f, B2f;
    #pragma unroll
    for (int r = 0; r < 4; ++r) {
        int k0 = 8 * h + 2 * r, k1 = k0 + 1;
        B1f.u[r] = (k0 == n ? 0x3F80u : 0u) | ((k1 == n ? 0x3F80u : 0u) << 16);
        B2f.u[r] = (k0 + 16 == n ? 0x3F80u : 0u) | ((k1 + 16 == n ? 0x3F80u : 0u) << 16);
    }

    float fcur = fb[(size_t)tm * LN + n];
    int   sc   = 0;                       // accumulated pow2 exponent (per column)
    f32x16 ZR;
    #pragma unroll
    for (int i = 0; i < 16; ++i) ZR[i] = 0.f;
    f32x16 C;

    for (int t = tm; t < te; ++t) {
        // ---- prefetch feat[t+1] (clamped on last iter; discarded) ----
        const int tn2 = (t + 1 < te) ? (t + 1) : t;
        float fnx = fb[(size_t)tn2 * LN + n];

        // ---- A = exp(trans + feat_t[row] - K); row factor lane-constant ----
        float F = __expf(fcur);
        union BU A1, A2;
        #pragma unroll
        for (int r = 0; r < 4; ++r) {
            A1.u[r] = pktrunc(E[2 * r] * F,     E[2 * r + 1] * F);
            A2.u[r] = pktrunc(E[8 + 2 * r] * F, E[9 + 2 * r] * F);
        }

        C = __builtin_amdgcn_mfma_f32_32x32x16_bf16(A1.v, B1f.v, ZR, 0, 0, 0);
        C = __builtin_amdgcn_mfma_f32_32x32x16_bf16(A2.v, B2f.v, C, 0, 0, 0);

        // ---- per-column pow2 rescale every 8 steps (exact; diag commutes) ----
        if ((t & 7) == 7) {
            float cm = C[0];
            #pragma unroll
            for (int i = 1; i < 16; ++i) cm = fmaxf(cm, C[i]);
            unsigned ca = __float_as_uint(cm), cb = ca;
            PLSWAP(ca, cb);                              // column consensus across halves
            cm = fmaxf(__uint_as_float(ca), __uint_as_float(cb));
            cm = fmaxf(cm, 1e-30f);
            int ex; frexpf(cm, &ex);
            sc += ex;
            #pragma unroll
            for (int i = 0; i < 16; ++i) C[i] = ldexpf(C[i], -ex);
        }

        // ---- C (col=l&31, row=(r&3)+8*(r>>2)+4h) -> next-step B operands ----
        unsigned PK[8];
        #pragma unroll
        for (int r = 0; r < 8; ++r) PK[r] = pktrunc(C[2 * r], C[2 * r + 1]);
        PLSWAP(PK[0], PK[2]);  PLSWAP(PK[1], PK[3]);
        PLSWAP(PK[4], PK[6]);  PLSWAP(PK[5], PK[7]);
        B1f.u[0] = PK[0]; B1f.u[1] = PK[1]; B1f.u[2] = PK[2]; B1f.u[3] = PK[3];
        B2f.u[0] = PK[4]; B2f.u[1] = PK[5]; B2f.u[2] = PK[6]; B2f.u[3] = PK[7];

        fcur = fnx;
    }

    // write log-space chunk matrix: log(true) = ln(C) + sc*ln2 + K*steps
    const float add = KSHIFT * (float)(te - tm) + (float)sc * LN2F;
    float* __restrict__ w = ws + ((size_t)gid << 10);
    #pragma unroll
    for (int r = 0; r < 16; ++r) {
        int row = (r & 3) + 8 * (r >> 2) + 4 * h;
        float v = C[r];
        w[row * LN + n] = (v > 0.f) ? (__logf(v) + add) : -10000.0f;
    }
}

// ---------------- Phase 2: log-space combine + final lse ----------------
__global__ __launch_bounds__(64) void crf_combine(
    const float* __restrict__ trans,
    const float* __restrict__ feat,
    const float* __restrict__ ws,
    float* __restrict__ out,
    int CHS)
{
    const int CH = 1 << CHS;
    const int l = threadIdx.x & 63, i = l & 31;
    const int seq = blockIdx.x * 2 + (l >> 5);
    const int bb = (l & 32) << 2;   // group-local bpermute base

    // alpha_1[i] = trans[i][0] + feat[1][i]  (exact)
    float alpha = trans[i * LN] + feat[(size_t)seq * TN * LN + LN + i];
    const float* __restrict__ wsb = ws + ((size_t)seq << (10 + CHS));

    for (int c = 0; c < CH; ++c) {
        const float4* Mr = (const float4*)(wsb + (c << 10) + i * LN);
        float vv[32];
        #pragma unroll
        for (int q = 0; q < 8; ++q) {
            float4 m4 = Mr[q];
            vv[4 * q + 0] = m4.x; vv[4 * q + 1] = m4.y;
            vv[4 * q + 2] = m4.z; vv[4 * q + 3] = m4.w;
        }
        float mx = -1e30f;
        #pragma unroll
        for (int j = 0; j < 32; ++j) {
            int r = __builtin_amdgcn_ds_bpermute(bb + (j << 2), __float_as_int(alpha));
            vv[j] += __int_as_float(r);
            mx = fmaxf(mx, vv[j]);
        }
        float s = 0.f;
        #pragma unroll
        for (int j = 0; j < 32; ++j) s += __expf(vv[j] - mx);
        alpha = mx + __logf(s);
    }

    // forward score = lse over 32 states
    float m = alpha;
    #pragma unroll
    for (int s = 16; s; s >>= 1) m = fmaxf(m, __shfl_xor(m, s, 32));
    float es = __expf(alpha - m);
    #pragma unroll
    for (int s = 16; s; s >>= 1) es += __shfl_xor(es, s, 32);
    float fs = m + __logf(es);

    if (i == 0) atomicAdd(out, fs * (1.0f / (float)BN));
}

extern "C" void kernel_launch(void* const* d_in, const int* in_sizes, int n_in,
                              void* d_out, int out_size, void* d_ws, size_t ws_size,
                              hipStream_t stream) {
    const float* features    = (const float*)d_in[0];
    const float* transitions = (const float*)d_in[1];
    const int*   labels      = (const int*)d_in[2];
    float* out = (float*)d_out;
    float* ws  = (float*)d_ws;

    int CHS = 3;
    while (CHS > 0 && ws_size < (((size_t)BN << CHS) * (LN * LN * 4))) --CHS;
    const int CH = 1 << CHS;

    hipMemsetAsync(out, 0, sizeof(float), stream);
    crf_chunk<<<dim3((BN * CH) / 4), dim3(256), 0, stream>>>(
        features, transitions, labels, ws, out, CHS);
    crf_combine<<<dim3(BN / 2), dim3(64), 0, stream>>>(
        transitions, features, ws, out, CHS);
}

// Round 11
// 183.328 us; speedup vs baseline: 1.7337x; 1.3913x over previous
//
#include <hip/hip_runtime.h>
#include <hip/hip_bf16.h>

// CRF loss via associative chunked scan (MFMA layouts verified R2-R9).
// R11 = R10's hand-written asm loop with three fixes:
//  (a) FB/NQ operands laundered through readfirstlane -> provably uniform ->
//      "s" constraints legal (R10 compile failure: divergent "s" -> VGPR).
//  (b) RESCALE moved INSIDE the 8th step between ABUILD and PACKSWAP
//      (R10 ordering scaled C after B was already repacked -> underflow bug).
//  (c) s_nop after v_exp_f32 and before permlane consensus (hazard margin).
// Fixed map: C=v[32:47], B=v[48:55], A dbuf=v[56:63]/v[64:71],
// feat ring=v[72:79] (depth 8, vmcnt(7)), temps v80-87, zeros v[88:103].

constexpr int BN = 1024, TN = 1024, LN = 32;
constexpr float KSHIFT = 8.5f;
constexpr float LN2F   = 0.69314718056f;

typedef __attribute__((ext_vector_type(8)))  short bf16x8;
typedef __attribute__((ext_vector_type(16))) float f32x16;

static __device__ __forceinline__ unsigned pktrunc(float a, float b) {
    return __builtin_amdgcn_perm(__float_as_uint(b), __float_as_uint(a), 0x07060302u);
}
#define PLSWAP(a, b) asm("v_permlane32_swap_b32 %0, %1" : "+v"(a), "+v"(b))

// ---------------- asm building blocks (fixed registers) ----------------
#define MFMA_PAIR(AR1, AR2) \
  "s_nop 1\n" \
  "v_mfma_f32_32x32x16_bf16 v[32:47], v[" AR1 "], v[48:51], v[88:103]\n" \
  "v_mfma_f32_32x32x16_bf16 v[32:47], v[" AR2 "], v[52:55], v[32:47]\n"

#define LOADF(VRL) \
  "v_min_u32 v82, v87, v81\n" \
  "global_load_dword " VRL ", v82, %[FB]\n" \
  "v_add_u32 v81, 0x80, v81\n" \
  "s_waitcnt vmcnt(7)\n"

#define EXPF(VR1) \
  "v_mul_f32 v80, 0x3fb8aa3b, " VR1 "\n" \
  "v_exp_f32 v80, v80\n" \
  "s_nop 0\n"

#define ABUILD(d0,d1,d2,d3,d4,d5,d6,d7) \
  "v_mul_f32 v83, %[E0], v80\n"  "v_mul_f32 v84, %[E1], v80\n"  "v_perm_b32 " d0 ", v84, v83, s28\n" \
  "v_mul_f32 v83, %[E2], v80\n"  "v_mul_f32 v84, %[E3], v80\n"  "v_perm_b32 " d1 ", v84, v83, s28\n" \
  "v_mul_f32 v83, %[E4], v80\n"  "v_mul_f32 v84, %[E5], v80\n"  "v_perm_b32 " d2 ", v84, v83, s28\n" \
  "v_mul_f32 v83, %[E6], v80\n"  "v_mul_f32 v84, %[E7], v80\n"  "v_perm_b32 " d3 ", v84, v83, s28\n" \
  "v_mul_f32 v83, %[E8], v80\n"  "v_mul_f32 v84, %[E9], v80\n"  "v_perm_b32 " d4 ", v84, v83, s28\n" \
  "v_mul_f32 v83, %[E10], v80\n" "v_mul_f32 v84, %[E11], v80\n" "v_perm_b32 " d5 ", v84, v83, s28\n" \
  "v_mul_f32 v83, %[E12], v80\n" "v_mul_f32 v84, %[E13], v80\n" "v_perm_b32 " d6 ", v84, v83, s28\n" \
  "v_mul_f32 v83, %[E14], v80\n" "v_mul_f32 v84, %[E15], v80\n" "v_perm_b32 " d7 ", v84, v83, s28\n"

#define PACKSWAP() \
  "v_perm_b32 v48, v33, v32, s28\n" \
  "v_perm_b32 v49, v35, v34, s28\n" \
  "v_perm_b32 v50, v37, v36, s28\n" \
  "v_perm_b32 v51, v39, v38, s28\n" \
  "v_perm_b32 v52, v41, v40, s28\n" \
  "v_perm_b32 v53, v43, v42, s28\n" \
  "v_perm_b32 v54, v45, v44, s28\n" \
  "v_perm_b32 v55, v47, v46, s28\n" \
  "v_permlane32_swap_b32 v48, v50\n" \
  "v_permlane32_swap_b32 v49, v51\n" \
  "v_permlane32_swap_b32 v52, v54\n" \
  "v_permlane32_swap_b32 v53, v55\n"

#define RESCALE() \
  "v_max_f32 v83, v32, v33\n" "v_max_f32 v84, v34, v35\n" "v_max_f32 v83, v83, v84\n" \
  "v_max_f32 v84, v36, v37\n" "v_max_f32 v85, v38, v39\n" "v_max_f32 v84, v84, v85\n" \
  "v_max_f32 v83, v83, v84\n" \
  "v_max_f32 v84, v40, v41\n" "v_max_f32 v85, v42, v43\n" "v_max_f32 v84, v84, v85\n" \
  "v_max_f32 v83, v83, v84\n" \
  "v_max_f32 v84, v44, v45\n" "v_max_f32 v85, v46, v47\n" "v_max_f32 v84, v84, v85\n" \
  "v_max_f32 v83, v83, v84\n" \
  "v_mov_b32 v84, v83\n" \
  "s_nop 1\n" \
  "v_permlane32_swap_b32 v83, v84\n" \
  "s_nop 1\n" \
  "v_max_f32 v83, v83, v84\n" \
  "v_max_f32 v83, 0x00800000, v83\n" \
  "v_frexp_exp_i32_f32 v85, v83\n" \
  "v_add_u32 v86, v85, v86\n" \
  "v_sub_u32 v85, 0, v85\n" \
  "v_ldexp_f32 v32, v32, v85\n" "v_ldexp_f32 v33, v33, v85\n" \
  "v_ldexp_f32 v34, v34, v85\n" "v_ldexp_f32 v35, v35, v85\n" \
  "v_ldexp_f32 v36, v36, v85\n" "v_ldexp_f32 v37, v37, v85\n" \
  "v_ldexp_f32 v38, v38, v85\n" "v_ldexp_f32 v39, v39, v85\n" \
  "v_ldexp_f32 v40, v40, v85\n" "v_ldexp_f32 v41, v41, v85\n" \
  "v_ldexp_f32 v42, v42, v85\n" "v_ldexp_f32 v43, v43, v85\n" \
  "v_ldexp_f32 v44, v44, v85\n" "v_ldexp_f32 v45, v45, v85\n" \
  "v_ldexp_f32 v46, v46, v85\n" "v_ldexp_f32 v47, v47, v85\n"

// even step: MFMA uses A in v[56:63], builds A' into v64..71; odd: converse
#define STEP_E(VRL, VR1) \
  MFMA_PAIR("56:59","60:63") LOADF(VRL) EXPF(VR1) \
  ABUILD("v64","v65","v66","v67","v68","v69","v70","v71") PACKSWAP()
#define STEP_O(VRL, VR1) \
  MFMA_PAIR("64:67","68:71") LOADF(VRL) EXPF(VR1) \
  ABUILD("v56","v57","v58","v59","v60","v61","v62","v63") PACKSWAP()
// 8th step: rescale C BEFORE repacking it into B (order verified in R3)
#define STEP_O_RS(VRL, VR1) \
  MFMA_PAIR("64:67","68:71") LOADF(VRL) EXPF(VR1) \
  ABUILD("v56","v57","v58","v59","v60","v61","v62","v63") RESCALE() PACKSWAP()

// ---------------- Phase 1: chunk transfer-matrix products ----------------
__global__ __launch_bounds__(256) void crf_chunk(
    const float* __restrict__ feat, const float* __restrict__ trans,
    const int* __restrict__ lab, float* __restrict__ ws,
    float* __restrict__ out, int CHS)
{
    const int CH = 1 << CHS, LEN = TN >> CHS;
    const int l = threadIdx.x & 63, n = l & 31, h = l >> 5;
    const int gid = blockIdx.x * 4 + (threadIdx.x >> 6);
    const int c = gid & (CH - 1), b = gid >> CHS;

    const float* __restrict__ fb = feat + (size_t)b * TN * LN;
    const int*   __restrict__ lb = lab  + (size_t)b * TN;

    const int start = c * LEN, te = start + LEN;
    const int tm = (c == 0) ? 2 : start;

    // ---- gold path: vectorized gather (verified R5-R9) ----
    {
        float gsum = 0.f;
        for (int r = 0; r < LEN; r += 64) {
            int t = start + r + l;
            if (t >= 1) {
                int cur = lb[t];
                gsum += trans[cur * LN + lb[t - 1]] + fb[(size_t)t * LN + cur];
            }
        }
        #pragma unroll
        for (int s = 32; s; s >>= 1) gsum += __shfl_xor(gsum, s, 64);
        if (l == 0) atomicAdd(out, -gsum * (1.0f / (float)BN));
    }

    // E constants (R3 ordering)
    float Ea[16];
    #pragma unroll
    for (int e = 0; e < 8; ++e) Ea[e]     = __expf(trans[n * LN + 8 * h + e]      - KSHIFT);
    #pragma unroll
    for (int e = 0; e < 8; ++e) Ea[8 + e] = __expf(trans[n * LN + 16 + 8 * h + e] - KSHIFT);

    // Running product as B operand; init Identity.
    union BU { bf16x8 v; unsigned u[4]; } B1f, B2f;
    #pragma unroll
    for (int r = 0; r < 4; ++r) {
        int k0 = 8 * h + 2 * r, k1 = k0 + 1;
        B1f.u[r] = (k0 == n ? 0x3F80u : 0u) | ((k1 == n ? 0x3F80u : 0u) << 16);
        B2f.u[r] = (k0 + 16 == n ? 0x3F80u : 0u) | ((k1 + 16 == n ? 0x3F80u : 0u) << 16);
    }

    // ---- chunk0: 6 HIP prologue steps (R3-verified path, no rescale) ----
    if (c == 0) {
        f32x16 ZR;
        #pragma unroll
        for (int i = 0; i < 16; ++i) ZR[i] = 0.f;
        for (int t = 2; t < 8; ++t) {
            float F = __expf(fb[(size_t)t * LN + n]);
            union BU A1, A2;
            #pragma unroll
            for (int r = 0; r < 4; ++r) {
                A1.u[r] = pktrunc(Ea[2 * r] * F,     Ea[2 * r + 1] * F);
                A2.u[r] = pktrunc(Ea[8 + 2 * r] * F, Ea[9 + 2 * r] * F);
            }
            f32x16 C;
            C = __builtin_amdgcn_mfma_f32_32x32x16_bf16(A1.v, B1f.v, ZR, 0, 0, 0);
            C = __builtin_amdgcn_mfma_f32_32x32x16_bf16(A2.v, B2f.v, C, 0, 0, 0);
            unsigned PK[8];
            #pragma unroll
            for (int r = 0; r < 8; ++r) PK[r] = pktrunc(C[2 * r], C[2 * r + 1]);
            PLSWAP(PK[0], PK[2]);  PLSWAP(PK[1], PK[3]);
            PLSWAP(PK[4], PK[6]);  PLSWAP(PK[5], PK[7]);
            B1f.u[0] = PK[0]; B1f.u[1] = PK[1]; B1f.u[2] = PK[2]; B1f.u[3] = PK[3];
            B2f.u[0] = PK[4]; B2f.u[1] = PK[5]; B2f.u[2] = PK[6]; B2f.u[3] = PK[7];
        }
    }

    const int tASM = (c == 0) ? 8 : start;
    const int nq   = (te - tASM) >> 3;                       // (LEN-8)/8 or LEN/8
    const float* fbC = fb + (size_t)start * LN;              // chunk base
    unsigned voff0  = (unsigned)((tASM - start) * (LN * 4) + n * 4);
    unsigned voffmx = (unsigned)((TN - 1 - start) * (LN * 4) + n * 4);

    // launder wave-uniform values so "s" constraints are provably uniform
    unsigned long long fbu = (unsigned long long)(uintptr_t)fbC;
    unsigned fblo = __builtin_amdgcn_readfirstlane((unsigned)fbu);
    unsigned fbhi = __builtin_amdgcn_readfirstlane((unsigned)(fbu >> 32));
    unsigned long long fbs = ((unsigned long long)fbhi << 32) | fblo;
    int nqs = __builtin_amdgcn_readfirstlane(nq);

    float co[16]; int scv;

    asm volatile(
        "s_waitcnt vmcnt(0)\n"
        "s_mov_b32 s28, 0x07060302\n"
        "v_mov_b32 v86, 0\n"
        "v_mov_b32 v88, 0\n"  "v_mov_b32 v89, 0\n"  "v_mov_b32 v90, 0\n"  "v_mov_b32 v91, 0\n"
        "v_mov_b32 v92, 0\n"  "v_mov_b32 v93, 0\n"  "v_mov_b32 v94, 0\n"  "v_mov_b32 v95, 0\n"
        "v_mov_b32 v96, 0\n"  "v_mov_b32 v97, 0\n"  "v_mov_b32 v98, 0\n"  "v_mov_b32 v99, 0\n"
        "v_mov_b32 v100, 0\n" "v_mov_b32 v101, 0\n" "v_mov_b32 v102, 0\n" "v_mov_b32 v103, 0\n"
        "v_mov_b32 v48, %[B0]\n" "v_mov_b32 v49, %[B1]\n" "v_mov_b32 v50, %[B2]\n" "v_mov_b32 v51, %[B3]\n"
        "v_mov_b32 v52, %[B4]\n" "v_mov_b32 v53, %[B5]\n" "v_mov_b32 v54, %[B6]\n" "v_mov_b32 v55, %[B7]\n"
        "v_mov_b32 v81, %[VO]\n"
        "v_mov_b32 v87, %[VM]\n"
        // ring preload: slots 0..7
        "v_min_u32 v82, v87, v81\n" "global_load_dword v72, v82, %[FB]\n" "v_add_u32 v81, 0x80, v81\n"
        "v_min_u32 v82, v87, v81\n" "global_load_dword v73, v82, %[FB]\n" "v_add_u32 v81, 0x80, v81\n"
        "v_min_u32 v82, v87, v81\n" "global_load_dword v74, v82, %[FB]\n" "v_add_u32 v81, 0x80, v81\n"
        "v_min_u32 v82, v87, v81\n" "global_load_dword v75, v82, %[FB]\n" "v_add_u32 v81, 0x80, v81\n"
        "v_min_u32 v82, v87, v81\n" "global_load_dword v76, v82, %[FB]\n" "v_add_u32 v81, 0x80, v81\n"
        "v_min_u32 v82, v87, v81\n" "global_load_dword v77, v82, %[FB]\n" "v_add_u32 v81, 0x80, v81\n"
        "v_min_u32 v82, v87, v81\n" "global_load_dword v78, v82, %[FB]\n" "v_add_u32 v81, 0x80, v81\n"
        "v_min_u32 v82, v87, v81\n" "global_load_dword v79, v82, %[FB]\n" "v_add_u32 v81, 0x80, v81\n"
        "s_waitcnt vmcnt(7)\n"
        EXPF("v72")
        ABUILD("v56","v57","v58","v59","v60","v61","v62","v63")   // A(step0) -> even
        "s_mov_b32 s20, 0\n"
        "CRFLOOP%=:\n"
        STEP_E("v72","v73")
        STEP_O("v73","v74")
        STEP_E("v74","v75")
        STEP_O("v75","v76")
        STEP_E("v76","v77")
        STEP_O("v77","v78")
        STEP_E("v78","v79")
        STEP_O_RS("v79","v72")
        "s_add_u32 s20, s20, 1\n"
        "s_cmp_lt_u32 s20, %[NQ]\n"
        "s_cbranch_scc1 CRFLOOP%=\n"
        "s_waitcnt vmcnt(0)\n"
        "v_mov_b32 %[C0], v32\n"  "v_mov_b32 %[C1], v33\n"  "v_mov_b32 %[C2], v34\n"  "v_mov_b32 %[C3], v35\n"
        "v_mov_b32 %[C4], v36\n"  "v_mov_b32 %[C5], v37\n"  "v_mov_b32 %[C6], v38\n"  "v_mov_b32 %[C7], v39\n"
        "v_mov_b32 %[C8], v40\n"  "v_mov_b32 %[C9], v41\n"  "v_mov_b32 %[C10], v42\n" "v_mov_b32 %[C11], v43\n"
        "v_mov_b32 %[C12], v44\n" "v_mov_b32 %[C13], v45\n" "v_mov_b32 %[C14], v46\n" "v_mov_b32 %[C15], v47\n"
        "v_mov_b32 %[SC], v86\n"
        : [C0]"=v"(co[0]),  [C1]"=v"(co[1]),  [C2]"=v"(co[2]),  [C3]"=v"(co[3]),
          [C4]"=v"(co[4]),  [C5]"=v"(co[5]),  [C6]"=v"(co[6]),  [C7]"=v"(co[7]),
          [C8]"=v"(co[8]),  [C9]"=v"(co[9]),  [C10]"=v"(co[10]),[C11]"=v"(co[11]),
          [C12]"=v"(co[12]),[C13]"=v"(co[13]),[C14]"=v"(co[14]),[C15]"=v"(co[15]),
          [SC]"=v"(scv)
        : [E0]"v"(Ea[0]),  [E1]"v"(Ea[1]),  [E2]"v"(Ea[2]),  [E3]"v"(Ea[3]),
          [E4]"v"(Ea[4]),  [E5]"v"(Ea[5]),  [E6]"v"(Ea[6]),  [E7]"v"(Ea[7]),
          [E8]"v"(Ea[8]),  [E9]"v"(Ea[9]),  [E10]"v"(Ea[10]),[E11]"v"(Ea[11]),
          [E12]"v"(Ea[12]),[E13]"v"(Ea[13]),[E14]"v"(Ea[14]),[E15]"v"(Ea[15]),
          [B0]"v"(B1f.u[0]), [B1]"v"(B1f.u[1]), [B2]"v"(B1f.u[2]), [B3]"v"(B1f.u[3]),
          [B4]"v"(B2f.u[0]), [B5]"v"(B2f.u[1]), [B6]"v"(B2f.u[2]), [B7]"v"(B2f.u[3]),
          [VO]"v"(voff0), [VM]"v"(voffmx), [FB]"s"(fbs), [NQ]"s"(nqs)
        : "memory","scc","s20","s28",
          "v32","v33","v34","v35","v36","v37","v38","v39",
          "v40","v41","v42","v43","v44","v45","v46","v47",
          "v48","v49","v50","v51","v52","v53","v54","v55",
          "v56","v57","v58","v59","v60","v61","v62","v63",
          "v64","v65","v66","v67","v68","v69","v70","v71",
          "v72","v73","v74","v75","v76","v77","v78","v79",
          "v80","v81","v82","v83","v84","v85","v86","v87",
          "v88","v89","v90","v91","v92","v93","v94","v95",
          "v96","v97","v98","v99","v100","v101","v102","v103");

    // write log-space chunk matrix: log = ln(C) + sc*ln2 + K*steps
    const float add = KSHIFT * (float)(te - tm) + (float)scv * LN2F;
    float* __restrict__ w = ws + ((size_t)gid << 10);
    #pragma unroll
    for (int r = 0; r < 16; ++r) {
        int row = (r & 3) + 8 * (r >> 2) + 4 * h;
        float v = co[r];
        w[row * LN + n] = (v > 0.f) ? (__logf(v) + add) : -10000.0f;
    }
}

// ---------------- Phase 2: log-space combine + final lse ----------------
__global__ __launch_bounds__(64) void crf_combine(
    const float* __restrict__ trans, const float* __restrict__ feat,
    const float* __restrict__ ws, float* __restrict__ out, int CHS)
{
    const int CH = 1 << CHS;
    const int l = threadIdx.x & 63, i = l & 31;
    const int seq = blockIdx.x * 2 + (l >> 5);
    const int bb = (l & 32) << 2;

    float alpha = trans[i * LN] + feat[(size_t)seq * TN * LN + LN + i];
    const float* __restrict__ wsb = ws + ((size_t)seq << (10 + CHS));

    for (int c = 0; c < CH; ++c) {
        const float4* Mr = (const float4*)(wsb + (c << 10) + i * LN);
        float vv[32];
        #pragma unroll
        for (int q = 0; q < 8; ++q) {
            float4 m4 = Mr[q];
            vv[4 * q + 0] = m4.x; vv[4 * q + 1] = m4.y;
            vv[4 * q + 2] = m4.z; vv[4 * q + 3] = m4.w;
        }
        float mx = -1e30f;
        #pragma unroll
        for (int j = 0; j < 32; ++j) {
            int r = __builtin_amdgcn_ds_bpermute(bb + (j << 2), __float_as_int(alpha));
            vv[j] += __int_as_float(r);
            mx = fmaxf(mx, vv[j]);
        }
        float s = 0.f;
        #pragma unroll
        for (int j = 0; j < 32; ++j) s += __expf(vv[j] - mx);
        alpha = mx + __logf(s);
    }

    float m = alpha;
    #pragma unroll
    for (int s = 16; s; s >>= 1) m = fmaxf(m, __shfl_xor(m, s, 32));
    float es = __expf(alpha - m);
    #pragma unroll
    for (int s = 16; s; s >>= 1) es += __shfl_xor(es, s, 32);
    float fs = m + __logf(es);

    if (i == 0) atomicAdd(out, fs * (1.0f / (float)BN));
}

extern "C" void kernel_launch(void* const* d_in, const int* in_sizes, int n_in,
                              void* d_out, int out_size, void* d_ws, size_t ws_size,
                              hipStream_t stream) {
    const float* features    = (const float*)d_in[0];
    const float* transitions = (const float*)d_in[1];
    const int*   labels      = (const int*)d_in[2];
    float* out = (float*)d_out;
    float* ws  = (float*)d_ws;

    int CHS = 3;
    while (CHS > 0 && ws_size < (((size_t)BN << CHS) * (LN * LN * 4))) --CHS;
    const int CH = 1 << CHS;

    hipMemsetAsync(out, 0, sizeof(float), stream);
    crf_chunk<<<dim3((BN * CH) / 4), dim3(256), 0, stream>>>(
        features, transitions, labels, ws, out, CHS);
    crf_combine<<<dim3(BN / 2), dim3(64), 0, stream>>>(
        transitions, features, ws, out, CHS);
}